// Round 1
// baseline (382.836 us; speedup 1.0000x reference)
//
#include <hip/hip_runtime.h>

// ---------------------------------------------------------------------------
// MultiHeadSelfAttention: B=4, L=2048, H=8, DK=DV=64, fp32 in/out.
// Reference quirks: logits *= sqrt(DK)=8 (multiply, not divide);
// ctx flattened dv-major (i = dv*H + h) before the final projection.
// ---------------------------------------------------------------------------

typedef _Float16 half4v __attribute__((ext_vector_type(4)));
typedef _Float16 half8v __attribute__((ext_vector_type(8)));
typedef float    float4v __attribute__((ext_vector_type(4)));

#define BB   4
#define LL   2048
#define HH   8
#define DKV  64
#define NROW (BB * LL)            /* 8192 */
#define QSCALE 11.541560327111707f /* 8 * log2(e): folded into wq so the attn loop uses exp2 */

// ---------------- prep: x -> f16 ----------------
__global__ __launch_bounds__(256) void k_prep_x(const float* __restrict__ x,
                                                _Float16* __restrict__ xh) {
    int i = blockIdx.x * 256 + threadIdx.x;       // NROW*64/4 = 131072 threads
    float4v v = ((const float4v*)x)[i];
    half4v h;
    h[0] = (_Float16)v[0]; h[1] = (_Float16)v[1];
    h[2] = (_Float16)v[2]; h[3] = (_Float16)v[3];
    ((half4v*)xh)[i] = h;
}

// ---------------- prep: concat+transpose W (and bias) -> Wt[1536][64] f16 ----
__global__ __launch_bounds__(256) void k_prep_w(const float* __restrict__ wq, const float* __restrict__ bq,
                                                const float* __restrict__ wk, const float* __restrict__ bk,
                                                const float* __restrict__ wv, const float* __restrict__ bv,
                                                _Float16* __restrict__ wt, float* __restrict__ biasc) {
    int idx = blockIdx.x * 256 + threadIdx.x;     // 1536*64 = 98304
    int j = idx >> 6, i = idx & 63;
    const float* w; const float* bsrc; int jj; float sc = 1.0f;
    if (j < 512)       { w = wq; bsrc = bq; jj = j;        sc = QSCALE; }
    else if (j < 1024) { w = wk; bsrc = bk; jj = j - 512;  }
    else               { w = wv; bsrc = bv; jj = j - 1024; }
    wt[idx] = (_Float16)(w[i * 512 + jj] * sc);
    if (i == 0) biasc[j] = bsrc[jj] * sc;
}

// ---------------- prep: wo (dv-major rows) -> wo2t[64][512] f16, k = h*64+dv --
__global__ __launch_bounds__(256) void k_prep_wo(const float* __restrict__ wo,
                                                 _Float16* __restrict__ wo2t) {
    int idx = blockIdx.x * 256 + threadIdx.x;     // 64*512 = 32768
    int j = idx >> 9, k = idx & 511;
    int dv = k & 63, h = k >> 6;
    wo2t[idx] = (_Float16)wo[(dv * HH + h) * 64 + j];
}

// ---------------- QKV projection GEMM: [8192,64] @ [64,1536] ----------------
__global__ __launch_bounds__(256) void k_proj(const _Float16* __restrict__ xh,
                                              const _Float16* __restrict__ wt,
                                              const float* __restrict__ biasc,
                                              _Float16* __restrict__ qh,
                                              _Float16* __restrict__ kh,
                                              _Float16* __restrict__ vh) {
    int wid = threadIdx.x >> 6, lane = threadIdx.x & 63;
    int g = lane >> 4, c = lane & 15;
    int m0 = blockIdx.x * 64 + wid * 16;
    int n0 = blockIdx.y * 64;

    half8v a0 = *(const half8v*)(xh + (m0 + c) * 64 + g * 8);
    half8v a1 = *(const half8v*)(xh + (m0 + c) * 64 + 32 + g * 8);

    float4v acc[4] = {};
#pragma unroll
    for (int t = 0; t < 4; ++t) {
        const _Float16* wp = wt + (n0 + t * 16 + c) * 64 + g * 8;
        half8v b0 = *(const half8v*)(wp);
        half8v b1 = *(const half8v*)(wp + 32);
        acc[t] = __builtin_amdgcn_mfma_f32_16x16x32_f16(a0, b0, acc[t], 0, 0, 0);
        acc[t] = __builtin_amdgcn_mfma_f32_16x16x32_f16(a1, b1, acc[t], 0, 0, 0);
    }
#pragma unroll
    for (int t = 0; t < 4; ++t) {
        int j = n0 + t * 16 + c;
        float bias = biasc[j];
        int mat = j >> 9, jj = j & 511, h = jj >> 6, cc = jj & 63;
        _Float16* dst = (mat == 0) ? qh : ((mat == 1) ? kh : vh);
#pragma unroll
        for (int r = 0; r < 4; ++r) {
            int m = m0 + g * 4 + r;
            int b = m >> 11, l = m & 2047;
            dst[((b * HH + h) * LL + l) * 64 + cc] = (_Float16)(acc[t][r] + bias);
        }
    }
}

// ---------------- transpose V: [bh][l][dv] -> [bh][dv][l] ----------------
__global__ __launch_bounds__(256) void k_transv(const _Float16* __restrict__ vh,
                                                _Float16* __restrict__ vt) {
    __shared__ _Float16 tile[64][65];
    int bh = blockIdx.x, l0 = blockIdx.y * 64;
    const _Float16* src = vh + (bh * LL + l0) * 64;
    int t = threadIdx.x;
    int li = t >> 2, d0 = (t & 3) * 16;
    half8v v0 = *(const half8v*)(src + li * 64 + d0);
    half8v v1 = *(const half8v*)(src + li * 64 + d0 + 8);
#pragma unroll
    for (int j = 0; j < 8; ++j) { tile[li][d0 + j] = v0[j]; tile[li][d0 + 8 + j] = v1[j]; }
    __syncthreads();
    int dv = t >> 2, lc0 = (t & 3) * 16;
    half8v o0, o1;
#pragma unroll
    for (int j = 0; j < 8; ++j) { o0[j] = tile[lc0 + j][dv]; o1[j] = tile[lc0 + 8 + j][dv]; }
    _Float16* dst = vt + (bh * 64 + dv) * LL + l0 + lc0;
    *(half8v*)(dst)     = o0;
    *(half8v*)(dst + 8) = o1;
}

// ---------------- flash attention (swapped-operand, register-resident P) ----
// Per wave: 16 q-rows. S^T tile via mfma_16x16x32_f16(K,Q); softmax across the
// 4 lane-groups (shfl_xor 16/32); P stays in registers and feeds
// mfma_16x16x16f16(Vt, P) whose B-layout equals the S^T D-layout.
__global__ __launch_bounds__(256) void k_attn(const _Float16* __restrict__ qh,
                                              const _Float16* __restrict__ kh,
                                              const _Float16* __restrict__ vt,
                                              _Float16* __restrict__ ctx) {
    int wid = threadIdx.x >> 6, lane = threadIdx.x & 63;
    int g = lane >> 4, c = lane & 15;
    int qt = blockIdx.x * 4 + wid;
    int bh = qt >> 7;
    int q0 = (qt & 127) * 16;

    const _Float16* qp = qh + (bh * LL + q0) * 64;
    const _Float16* kp = kh + (size_t)bh * LL * 64;
    const _Float16* vp = vt + (size_t)bh * 64 * LL;

    half8v qf0 = *(const half8v*)(qp + c * 64 + g * 8);
    half8v qf1 = *(const half8v*)(qp + c * 64 + 32 + g * 8);

    float4v o[4] = {};
    float m = -1e30f, lsum = 0.0f;

    for (int kt = 0; kt < 128; ++kt) {
        const _Float16* kpp = kp + (kt * 16 + c) * 64 + g * 8;
        half8v kf0 = *(const half8v*)(kpp);
        half8v kf1 = *(const half8v*)(kpp + 32);
        float4v s = {};
        s = __builtin_amdgcn_mfma_f32_16x16x32_f16(kf0, qf0, s, 0, 0, 0);
        s = __builtin_amdgcn_mfma_f32_16x16x32_f16(kf1, qf1, s, 0, 0, 0);

        float pmax = fmaxf(fmaxf(s[0], s[1]), fmaxf(s[2], s[3]));
        pmax = fmaxf(pmax, __shfl_xor(pmax, 16));
        pmax = fmaxf(pmax, __shfl_xor(pmax, 32));

        if (__any(pmax > m + 3.0f)) {          // deferred rescale (T13)
            float mn = fmaxf(m, pmax);
            float sc = __builtin_amdgcn_exp2f(m - mn);
            lsum *= sc;
#pragma unroll
            for (int t = 0; t < 4; ++t) o[t] *= sc;
            m = mn;
        }

        float p0 = __builtin_amdgcn_exp2f(s[0] - m);
        float p1 = __builtin_amdgcn_exp2f(s[1] - m);
        float p2 = __builtin_amdgcn_exp2f(s[2] - m);
        float p3 = __builtin_amdgcn_exp2f(s[3] - m);
        lsum += (p0 + p1) + (p2 + p3);
        half4v ph;
        ph[0] = (_Float16)p0; ph[1] = (_Float16)p1;
        ph[2] = (_Float16)p2; ph[3] = (_Float16)p3;

        const _Float16* vpp = vp + (size_t)c * LL + kt * 16 + g * 4;
        half4v vf[4];
#pragma unroll
        for (int t = 0; t < 4; ++t) vf[t] = *(const half4v*)(vpp + (size_t)t * 16 * LL);
#pragma unroll
        for (int t = 0; t < 4; ++t)
            o[t] = __builtin_amdgcn_mfma_f32_16x16x16f16(vf[t], ph, o[t], 0, 0, 0);
    }

    lsum += __shfl_xor(lsum, 16);
    lsum += __shfl_xor(lsum, 32);
    float inv = 1.0f / lsum;

    _Float16* cp = ctx + ((size_t)bh * LL + q0 + c) * 64 + g * 4;
#pragma unroll
    for (int t = 0; t < 4; ++t) {
        half4v hv;
#pragma unroll
        for (int r = 0; r < 4; ++r) hv[r] = (_Float16)(o[t][r] * inv);
        *(half4v*)(cp + t * 16) = hv;
    }
}

// ---------------- output projection: [8192,512] @ [512,64] ----------------
__global__ __launch_bounds__(64) void k_oproj(const _Float16* __restrict__ ctx,
                                              const _Float16* __restrict__ wo2t,
                                              const float* __restrict__ bo,
                                              float* __restrict__ out) {
    int lane = threadIdx.x & 63;
    int g = lane >> 4, c = lane & 15;
    int m0 = blockIdx.x * 16;
    int b = m0 >> 11, l = m0 & 2047;
    const _Float16* cbase = ctx + ((size_t)b * HH * LL + l) * 64;

    float4v acc[4] = {};
#pragma unroll
    for (int kc = 0; kc < 16; ++kc) {
        int hh = kc >> 1;
        const _Float16* ap = cbase + (size_t)hh * LL * 64 + c * 64 + (kc & 1) * 32 + g * 8;
        half8v a = *(const half8v*)(ap);
#pragma unroll
        for (int t = 0; t < 4; ++t) {
            half8v bf = *(const half8v*)(wo2t + (t * 16 + c) * 512 + kc * 32 + g * 8);
            acc[t] = __builtin_amdgcn_mfma_f32_16x16x32_f16(a, bf, acc[t], 0, 0, 0);
        }
    }
#pragma unroll
    for (int t = 0; t < 4; ++t) {
        float bias = bo[t * 16 + c];
#pragma unroll
        for (int r = 0; r < 4; ++r) {
            int mm = m0 + g * 4 + r;
            out[mm * 64 + t * 16 + c] = acc[t][r] + bias;
        }
    }
}

// ---------------------------------------------------------------------------
extern "C" void kernel_launch(void* const* d_in, const int* in_sizes, int n_in,
                              void* d_out, int out_size, void* d_ws, size_t ws_size,
                              hipStream_t stream) {
    const float* x  = (const float*)d_in[0];
    const float* wq = (const float*)d_in[1];
    const float* bq = (const float*)d_in[2];
    const float* wk = (const float*)d_in[3];
    const float* bk = (const float*)d_in[4];
    const float* wv = (const float*)d_in[5];
    const float* bv = (const float*)d_in[6];
    const float* wo = (const float*)d_in[7];
    const float* bo = (const float*)d_in[8];
    float* out = (float*)d_out;

    char* ws = (char*)d_ws;
    _Float16* xh    = (_Float16*)(ws);                       // 1 MB
    _Float16* wt    = (_Float16*)(ws + 1048576);             // 192 KB
    float*    biasc = (float*)   (ws + 1245184);             // 6 KB
    _Float16* wo2t  = (_Float16*)(ws + 1251328);             // 64 KB
    _Float16* qh    = (_Float16*)(ws + 1316864);             // 8 MB
    _Float16* kh    = (_Float16*)(ws + 1316864 + 1ull * 8388608);
    _Float16* vh    = (_Float16*)(ws + 1316864 + 2ull * 8388608);
    _Float16* vt    = (_Float16*)(ws + 1316864 + 3ull * 8388608);
    _Float16* ctx   = (_Float16*)(ws + 1316864 + 4ull * 8388608);

    hipLaunchKernelGGL(k_prep_x,  dim3(512),      dim3(256), 0, stream, x, xh);
    hipLaunchKernelGGL(k_prep_w,  dim3(384),      dim3(256), 0, stream, wq, bq, wk, bk, wv, bv, wt, biasc);
    hipLaunchKernelGGL(k_prep_wo, dim3(128),      dim3(256), 0, stream, wo, wo2t);
    hipLaunchKernelGGL(k_proj,    dim3(128, 24),  dim3(256), 0, stream, xh, wt, biasc, qh, kh, vh);
    hipLaunchKernelGGL(k_transv,  dim3(32, 32),   dim3(256), 0, stream, vh, vt);
    hipLaunchKernelGGL(k_attn,    dim3(1024),     dim3(256), 0, stream, qh, kh, vt, ctx);
    hipLaunchKernelGGL(k_oproj,   dim3(512),      dim3(64),  0, stream, ctx, wo2t, bo, out);
}

// Round 2
// 113.354 us; speedup vs baseline: 3.3774x; 3.3774x over previous
//
#include <hip/hip_runtime.h>

// ---------------------------------------------------------------------------
// MultiHeadSelfAttention: B=4, L=2048, H=8, DK=DV=64, fp32 in/out.
// Reference quirks: logits *= sqrt(DK)=8 (multiply, not divide);
// ctx flattened dv-major (i = dv*H + h) before the final projection.
// ---------------------------------------------------------------------------

typedef _Float16 half4v __attribute__((ext_vector_type(4)));
typedef _Float16 half8v __attribute__((ext_vector_type(8)));
typedef float    float4v __attribute__((ext_vector_type(4)));

#define BB   4
#define LL   2048
#define HH   8
#define DKV  64
#define NROW (BB * LL)            /* 8192 */
#define QSCALE 11.541560327111707f /* 8 * log2(e): folded into wq so the attn loop uses exp2 */

#define KVBLK 64
#define NKB   (LL / KVBLK)        /* 32 */

#define GLOAD_LDS(gp, sp) \
    __builtin_amdgcn_global_load_lds((const __attribute__((address_space(1))) void*)(gp), \
                                     (__attribute__((address_space(3))) void*)(sp), 16, 0, 0)

// ---------------- prep: x -> f16 ----------------
__global__ __launch_bounds__(256) void k_prep_x(const float* __restrict__ x,
                                                _Float16* __restrict__ xh) {
    int i = blockIdx.x * 256 + threadIdx.x;       // NROW*64/4 = 131072 threads
    float4v v = ((const float4v*)x)[i];
    half4v h;
    h[0] = (_Float16)v[0]; h[1] = (_Float16)v[1];
    h[2] = (_Float16)v[2]; h[3] = (_Float16)v[3];
    ((half4v*)xh)[i] = h;
}

// ---------------- prep: concat+transpose W (and bias) -> Wt[1536][64] f16 ----
__global__ __launch_bounds__(256) void k_prep_w(const float* __restrict__ wq, const float* __restrict__ bq,
                                                const float* __restrict__ wk, const float* __restrict__ bk,
                                                const float* __restrict__ wv, const float* __restrict__ bv,
                                                _Float16* __restrict__ wt, float* __restrict__ biasc) {
    int idx = blockIdx.x * 256 + threadIdx.x;     // 1536*64 = 98304
    int j = idx >> 6, i = idx & 63;
    const float* w; const float* bsrc; int jj; float sc = 1.0f;
    if (j < 512)       { w = wq; bsrc = bq; jj = j;        sc = QSCALE; }
    else if (j < 1024) { w = wk; bsrc = bk; jj = j - 512;  }
    else               { w = wv; bsrc = bv; jj = j - 1024; }
    wt[idx] = (_Float16)(w[i * 512 + jj] * sc);
    if (i == 0) biasc[j] = bsrc[jj] * sc;
}

// ---------------- prep: wo (dv-major rows) -> wo2t[64][512] f16, k = h*64+dv --
__global__ __launch_bounds__(256) void k_prep_wo(const float* __restrict__ wo,
                                                 _Float16* __restrict__ wo2t) {
    int idx = blockIdx.x * 256 + threadIdx.x;     // 64*512 = 32768
    int j = idx >> 9, k = idx & 511;
    int dv = k & 63, h = k >> 6;
    wo2t[idx] = (_Float16)wo[(dv * HH + h) * 64 + j];
}

// ---------------- QKV projection GEMM: [8192,64] @ [64,1536] ----------------
__global__ __launch_bounds__(256) void k_proj(const _Float16* __restrict__ xh,
                                              const _Float16* __restrict__ wt,
                                              const float* __restrict__ biasc,
                                              _Float16* __restrict__ qh,
                                              _Float16* __restrict__ kh,
                                              _Float16* __restrict__ vh) {
    int wid = threadIdx.x >> 6, lane = threadIdx.x & 63;
    int g = lane >> 4, c = lane & 15;
    int m0 = blockIdx.x * 64 + wid * 16;
    int n0 = blockIdx.y * 64;

    half8v a0 = *(const half8v*)(xh + (m0 + c) * 64 + g * 8);
    half8v a1 = *(const half8v*)(xh + (m0 + c) * 64 + 32 + g * 8);

    float4v acc[4] = {};
#pragma unroll
    for (int t = 0; t < 4; ++t) {
        const _Float16* wp = wt + (n0 + t * 16 + c) * 64 + g * 8;
        half8v b0 = *(const half8v*)(wp);
        half8v b1 = *(const half8v*)(wp + 32);
        acc[t] = __builtin_amdgcn_mfma_f32_16x16x32_f16(a0, b0, acc[t], 0, 0, 0);
        acc[t] = __builtin_amdgcn_mfma_f32_16x16x32_f16(a1, b1, acc[t], 0, 0, 0);
    }
#pragma unroll
    for (int t = 0; t < 4; ++t) {
        int j = n0 + t * 16 + c;
        float bias = biasc[j];
        int mat = j >> 9, jj = j & 511, h = jj >> 6, cc = jj & 63;
        _Float16* dst = (mat == 0) ? qh : ((mat == 1) ? kh : vh);
#pragma unroll
        for (int r = 0; r < 4; ++r) {
            int m = m0 + g * 4 + r;
            int b = m >> 11, l = m & 2047;
            dst[((b * HH + h) * LL + l) * 64 + cc] = (_Float16)(acc[t][r] + bias);
        }
    }
}

// ---------------- transpose V: [bh][l][dv] -> [bh][dv][l] ----------------
__global__ __launch_bounds__(256) void k_transv(const _Float16* __restrict__ vh,
                                                _Float16* __restrict__ vt) {
    __shared__ _Float16 tile[64][65];
    int bh = blockIdx.x, l0 = blockIdx.y * 64;
    const _Float16* src = vh + (bh * LL + l0) * 64;
    int t = threadIdx.x;
    int li = t >> 2, d0 = (t & 3) * 16;
    half8v v0 = *(const half8v*)(src + li * 64 + d0);
    half8v v1 = *(const half8v*)(src + li * 64 + d0 + 8);
#pragma unroll
    for (int j = 0; j < 8; ++j) { tile[li][d0 + j] = v0[j]; tile[li][d0 + 8 + j] = v1[j]; }
    __syncthreads();
    int dv = t >> 2, lc0 = (t & 3) * 16;
    half8v o0, o1;
#pragma unroll
    for (int j = 0; j < 8; ++j) { o0[j] = tile[lc0 + j][dv]; o1[j] = tile[lc0 + 8 + j][dv]; }
    _Float16* dst = vt + (bh * 64 + dv) * LL + l0 + lc0;
    *(half8v*)(dst)     = o0;
    *(half8v*)(dst + 8) = o1;
}

// ---------------- flash attention v2: LDS-staged K/V, 8 waves/block ----------
// Block = 512 threads = 8 waves; each wave owns 16 q-rows (128 q-rows/block,
// one bh per block). K/V tiles (KVBLK=64) staged to LDS via global_load_lds
// (16B, XOR-swizzled source per rule 21), double-buffered with counted
// vmcnt(2) prefetch + raw s_barrier (no vmcnt(0) drain in-loop).
// XCD-aware bid mapping keeps each head's K/V inside one XCD's L2.
__global__ __launch_bounds__(512) void k_attn(const _Float16* __restrict__ qh,
                                              const _Float16* __restrict__ kh,
                                              const _Float16* __restrict__ vt,
                                              _Float16* __restrict__ ctx) {
    __shared__ char lds[2 * 16384];   // buf: [K 8KB][V 8KB], x2 double-buffer

    int tid = threadIdx.x;
    int wid = tid >> 6, lane = tid & 63;
    int g = lane >> 4, c = lane & 15;

    // 512 blocks: xcd = bid%8 -> 4 heads per XCD (K+V = 2MB, L2-resident)
    int bid = blockIdx.x;
    int xcd = bid & 7;
    int rest = bid >> 3;                  // 0..63
    int bh = xcd * 4 + (rest >> 4);       // 0..31
    int qc = rest & 15;                   // 16 chunks of 128 q-rows
    int q0 = qc * 128 + wid * 16;

    const _Float16* qp = qh + ((size_t)bh * LL + q0) * 64;
    const char* kg = (const char*)(kh + (size_t)bh * LL * 64);   // [L][64] contiguous tile: 8KB per KVBLK
    const char* vg = (const char*)(vt + (size_t)bh * 64 * LL);   // [dv=64][L]

    half8v qf0 = *(const half8v*)(qp + c * 64 + g * 8);
    half8v qf1 = *(const half8v*)(qp + c * 64 + 32 + g * 8);

    // ---- staging geometry: 8 waves x 1KB per tile; HW writes ldsbase + lane*16
    int pK   = wid * 1024 + lane * 16;            // byte offset in 8KB tile
    int rowS = pK >> 7;                           // tile row (128B rows)
    int srcK = (pK & ~127) | ((pK & 127) ^ ((rowS & 7) << 4));   // pre-swizzled source
    size_t srcV = (size_t)rowS * (LL * 2) + (size_t)((pK & 127) ^ ((rowS & 7) << 4));

#define STAGE(buf, kb) do {                                                   \
        char* sK = lds + (buf) * 16384 + wid * 1024;                          \
        char* sV = lds + (buf) * 16384 + 8192 + wid * 1024;                   \
        GLOAD_LDS(kg + (size_t)(kb) * 8192 + srcK, sK);                       \
        GLOAD_LDS(vg + srcV + (size_t)(kb) * 128, sV);                        \
    } while (0)

    float4v o[4] = {};
    float m = -1e30f, lsum = 0.0f;
    int swzk_c = (c & 7) << 4;   // read-side swizzle term for V rows (row&7 == c&7)

    STAGE(0, 0);

    for (int kb = 0; kb < NKB; ++kb) {
        int cur = kb & 1;
        if (kb + 1 < NKB) {
            STAGE(cur ^ 1, kb + 1);
            asm volatile("s_waitcnt vmcnt(2)" ::: "memory");
        } else {
            asm volatile("s_waitcnt vmcnt(0)" ::: "memory");
        }
        asm volatile("s_barrier" ::: "memory");

        const char* lk = lds + cur * 16384;
        const char* lv = lk + 8192;

#pragma unroll
        for (int s = 0; s < 4; ++s) {
            int krow = s * 16 + c;
            int swzk = (krow & 7) << 4;    // == swzk_c, but keep explicit
            half8v kf0 = *(const half8v*)(lk + krow * 128 + ((g * 16) ^ swzk));
            half8v kf1 = *(const half8v*)(lk + krow * 128 + ((g * 16 + 64) ^ swzk));
            float4v sv = {};
            sv = __builtin_amdgcn_mfma_f32_16x16x32_f16(kf0, qf0, sv, 0, 0, 0);
            sv = __builtin_amdgcn_mfma_f32_16x16x32_f16(kf1, qf1, sv, 0, 0, 0);

            float pmax = fmaxf(fmaxf(sv[0], sv[1]), fmaxf(sv[2], sv[3]));
            pmax = fmaxf(pmax, __shfl_xor(pmax, 16));
            pmax = fmaxf(pmax, __shfl_xor(pmax, 32));

            if (__any(pmax > m + 3.0f)) {          // deferred rescale (T13)
                float mn = fmaxf(m, pmax);
                float sc = __builtin_amdgcn_exp2f(m - mn);
                lsum *= sc;
#pragma unroll
                for (int t = 0; t < 4; ++t) o[t] *= sc;
                m = mn;
            }

            float p0 = __builtin_amdgcn_exp2f(sv[0] - m);
            float p1 = __builtin_amdgcn_exp2f(sv[1] - m);
            float p2 = __builtin_amdgcn_exp2f(sv[2] - m);
            float p3 = __builtin_amdgcn_exp2f(sv[3] - m);
            lsum += (p0 + p1) + (p2 + p3);
            half4v ph;
            ph[0] = (_Float16)p0; ph[1] = (_Float16)p1;
            ph[2] = (_Float16)p2; ph[3] = (_Float16)p3;

            int vcol = (s * 32 + g * 8) ^ swzk_c;
#pragma unroll
            for (int t = 0; t < 4; ++t) {
                half4v vf = *(const half4v*)(lv + (t * 16 + c) * 128 + vcol);
                o[t] = __builtin_amdgcn_mfma_f32_16x16x16f16(vf, ph, o[t], 0, 0, 0);
            }
        }

        asm volatile("s_barrier" ::: "memory");
    }
#undef STAGE

    lsum += __shfl_xor(lsum, 16);
    lsum += __shfl_xor(lsum, 32);
    float inv = 1.0f / lsum;

    _Float16* cp = ctx + ((size_t)bh * LL + q0 + c) * 64 + g * 4;
#pragma unroll
    for (int t = 0; t < 4; ++t) {
        half4v hv;
#pragma unroll
        for (int r = 0; r < 4; ++r) hv[r] = (_Float16)(o[t][r] * inv);
        *(half4v*)(cp + t * 16) = hv;
    }
}

// ---------------- output projection: [8192,512] @ [512,64] ----------------
__global__ __launch_bounds__(64) void k_oproj(const _Float16* __restrict__ ctx,
                                              const _Float16* __restrict__ wo2t,
                                              const float* __restrict__ bo,
                                              float* __restrict__ out) {
    int lane = threadIdx.x & 63;
    int g = lane >> 4, c = lane & 15;
    int m0 = blockIdx.x * 16;
    int b = m0 >> 11, l = m0 & 2047;
    const _Float16* cbase = ctx + ((size_t)b * HH * LL + l) * 64;

    float4v acc[4] = {};
#pragma unroll
    for (int kc = 0; kc < 16; ++kc) {
        int hh = kc >> 1;
        const _Float16* ap = cbase + (size_t)hh * LL * 64 + c * 64 + (kc & 1) * 32 + g * 8;
        half8v a = *(const half8v*)(ap);
#pragma unroll
        for (int t = 0; t < 4; ++t) {
            half8v bf = *(const half8v*)(wo2t + (t * 16 + c) * 512 + kc * 32 + g * 8);
            acc[t] = __builtin_amdgcn_mfma_f32_16x16x32_f16(a, bf, acc[t], 0, 0, 0);
        }
    }
#pragma unroll
    for (int t = 0; t < 4; ++t) {
        float bias = bo[t * 16 + c];
#pragma unroll
        for (int r = 0; r < 4; ++r) {
            int mm = m0 + g * 4 + r;
            out[mm * 64 + t * 16 + c] = acc[t][r] + bias;
        }
    }
}

// ---------------------------------------------------------------------------
extern "C" void kernel_launch(void* const* d_in, const int* in_sizes, int n_in,
                              void* d_out, int out_size, void* d_ws, size_t ws_size,
                              hipStream_t stream) {
    const float* x  = (const float*)d_in[0];
    const float* wq = (const float*)d_in[1];
    const float* bq = (const float*)d_in[2];
    const float* wk = (const float*)d_in[3];
    const float* bk = (const float*)d_in[4];
    const float* wv = (const float*)d_in[5];
    const float* bv = (const float*)d_in[6];
    const float* wo = (const float*)d_in[7];
    const float* bo = (const float*)d_in[8];
    float* out = (float*)d_out;

    char* ws = (char*)d_ws;
    _Float16* xh    = (_Float16*)(ws);                       // 1 MB
    _Float16* wt    = (_Float16*)(ws + 1048576);             // 192 KB
    float*    biasc = (float*)   (ws + 1245184);             // 6 KB
    _Float16* wo2t  = (_Float16*)(ws + 1251328);             // 64 KB
    _Float16* qh    = (_Float16*)(ws + 1316864);             // 8 MB
    _Float16* kh    = (_Float16*)(ws + 1316864 + 1ull * 8388608);
    _Float16* vh    = (_Float16*)(ws + 1316864 + 2ull * 8388608);
    _Float16* vt    = (_Float16*)(ws + 1316864 + 3ull * 8388608);
    _Float16* ctx   = (_Float16*)(ws + 1316864 + 4ull * 8388608);

    hipLaunchKernelGGL(k_prep_x,  dim3(512),      dim3(256), 0, stream, x, xh);
    hipLaunchKernelGGL(k_prep_w,  dim3(384),      dim3(256), 0, stream, wq, bq, wk, bk, wv, bv, wt, biasc);
    hipLaunchKernelGGL(k_prep_wo, dim3(128),      dim3(256), 0, stream, wo, wo2t);
    hipLaunchKernelGGL(k_proj,    dim3(128, 24),  dim3(256), 0, stream, xh, wt, biasc, qh, kh, vh);
    hipLaunchKernelGGL(k_transv,  dim3(32, 32),   dim3(256), 0, stream, vh, vt);
    hipLaunchKernelGGL(k_attn,    dim3(512),      dim3(512), 0, stream, qh, kh, vt, ctx);
    hipLaunchKernelGGL(k_oproj,   dim3(512),      dim3(64),  0, stream, ctx, wo2t, bo, out);
}

// Round 7
// 110.037 us; speedup vs baseline: 3.4792x; 1.0301x over previous
//
#include <hip/hip_runtime.h>

// ---------------------------------------------------------------------------
// MultiHeadSelfAttention: B=4, L=2048, H=8, DK=DV=64, fp32 in/out.
// Reference quirks: logits *= sqrt(DK)=8 (multiply, not divide);
// ctx flattened dv-major (i = dv*H + h) before the final projection.
//
// BISECTION ROUND: k_attn is the round-2 kernel VERBATIM (known PASS @78us).
// Single change under test: k_proj writes V directly transposed (k_transv
// deleted). If this NaNs, the V^T write is the bug; if it passes, the bug
// is in {2nd Q-frag, ones-lsum-MFMA, 4-wave staging geometry}.
// ---------------------------------------------------------------------------

typedef _Float16 half4v __attribute__((ext_vector_type(4)));
typedef _Float16 half8v __attribute__((ext_vector_type(8)));
typedef float    float4v __attribute__((ext_vector_type(4)));

#define BB   4
#define LL   2048
#define HH   8
#define DKV  64
#define NROW (BB * LL)            /* 8192 */
#define QSCALE 11.541560327111707f /* 8 * log2(e): folded into wq so the attn loop uses exp2 */

#define KVBLK 64
#define NKB   (LL / KVBLK)        /* 32 */

#define GLOAD_LDS(gp, sp) \
    __builtin_amdgcn_global_load_lds((const __attribute__((address_space(1))) void*)(gp), \
                                     (__attribute__((address_space(3))) void*)(sp), 16, 0, 0)

// ---------------- prep: x -> f16 ----------------
__global__ __launch_bounds__(256) void k_prep_x(const float* __restrict__ x,
                                                _Float16* __restrict__ xh) {
    int i = blockIdx.x * 256 + threadIdx.x;       // NROW*64/4 = 131072 threads
    float4v v = ((const float4v*)x)[i];
    half4v h;
    h[0] = (_Float16)v[0]; h[1] = (_Float16)v[1];
    h[2] = (_Float16)v[2]; h[3] = (_Float16)v[3];
    ((half4v*)xh)[i] = h;
}

// ---------------- prep: concat+transpose W (and bias) -> Wt[1536][64] f16 ----
__global__ __launch_bounds__(256) void k_prep_w(const float* __restrict__ wq, const float* __restrict__ bq,
                                                const float* __restrict__ wk, const float* __restrict__ bk,
                                                const float* __restrict__ wv, const float* __restrict__ bv,
                                                _Float16* __restrict__ wt, float* __restrict__ biasc) {
    int idx = blockIdx.x * 256 + threadIdx.x;     // 1536*64 = 98304
    int j = idx >> 6, i = idx & 63;
    const float* w; const float* bsrc; int jj; float sc = 1.0f;
    if (j < 512)       { w = wq; bsrc = bq; jj = j;        sc = QSCALE; }
    else if (j < 1024) { w = wk; bsrc = bk; jj = j - 512;  }
    else               { w = wv; bsrc = bv; jj = j - 1024; }
    wt[idx] = (_Float16)(w[i * 512 + jj] * sc);
    if (i == 0) biasc[j] = bsrc[jj] * sc;
}

// ---------------- prep: wo (dv-major rows) -> wo2t[64][512] f16, k = h*64+dv --
__global__ __launch_bounds__(256) void k_prep_wo(const float* __restrict__ wo,
                                                 _Float16* __restrict__ wo2t) {
    int idx = blockIdx.x * 256 + threadIdx.x;     // 64*512 = 32768
    int j = idx >> 9, k = idx & 511;
    int dv = k & 63, h = k >> 6;
    wo2t[idx] = (_Float16)wo[(dv * HH + h) * 64 + j];
}

// ---------------- QKV projection GEMM: [8192,64] @ [64,1536] ----------------
// V is written directly TRANSPOSED into vt[bh][dv][l] (k_transv eliminated).
// <-- THE ONE CHANGE UNDER TEST THIS ROUND -->
__global__ __launch_bounds__(256) void k_proj(const _Float16* __restrict__ xh,
                                              const _Float16* __restrict__ wt,
                                              const float* __restrict__ biasc,
                                              _Float16* __restrict__ qh,
                                              _Float16* __restrict__ kh,
                                              _Float16* __restrict__ vtw) {
    int wid = threadIdx.x >> 6, lane = threadIdx.x & 63;
    int g = lane >> 4, c = lane & 15;
    int m0 = blockIdx.x * 64 + wid * 16;
    int n0 = blockIdx.y * 64;

    half8v a0 = *(const half8v*)(xh + (m0 + c) * 64 + g * 8);
    half8v a1 = *(const half8v*)(xh + (m0 + c) * 64 + 32 + g * 8);

    float4v acc[4] = {};
#pragma unroll
    for (int t = 0; t < 4; ++t) {
        const _Float16* wp = wt + (n0 + t * 16 + c) * 64 + g * 8;
        half8v b0 = *(const half8v*)(wp);
        half8v b1 = *(const half8v*)(wp + 32);
        acc[t] = __builtin_amdgcn_mfma_f32_16x16x32_f16(a0, b0, acc[t], 0, 0, 0);
        acc[t] = __builtin_amdgcn_mfma_f32_16x16x32_f16(a1, b1, acc[t], 0, 0, 0);
    }
#pragma unroll
    for (int t = 0; t < 4; ++t) {
        int j = n0 + t * 16 + c;
        float bias = biasc[j];
        int mat = j >> 9, jj = j & 511, h = jj >> 6;
        if (mat == 2) {
            // V: transposed write vt[(b*8+h)*64 + cc][l0 + g*4 .. +4], cc = t*16+c
            int b = m0 >> 11, l0 = m0 & 2047;
            half4v hv;
#pragma unroll
            for (int r = 0; r < 4; ++r) hv[r] = (_Float16)(acc[t][r] + bias);
            *(half4v*)(vtw + ((size_t)(b * 8 + h) * 64 + t * 16 + c) * 2048 + l0 + g * 4) = hv;
        } else {
            int cc = (t * 16 + c);
            _Float16* dst = (mat == 0) ? qh : kh;
#pragma unroll
            for (int r = 0; r < 4; ++r) {
                int m = m0 + g * 4 + r;
                int b = m >> 11, l = m & 2047;
                dst[((size_t)(b * HH + h) * LL + l) * 64 + cc] = (_Float16)(acc[t][r] + bias);
            }
        }
    }
}

// ---------------- flash attention: ROUND-2 VERBATIM (known PASS) -------------
// Block = 512 threads = 8 waves; each wave owns 16 q-rows (128 q-rows/block,
// one bh per block). K/V tiles (KVBLK=64) staged to LDS via global_load_lds
// (16B, XOR-swizzled source per rule 21), double-buffered with counted
// vmcnt(2) prefetch + raw s_barrier (no vmcnt(0) drain in-loop).
// XCD-aware bid mapping keeps each head's K/V inside one XCD's L2.
__global__ __launch_bounds__(512) void k_attn(const _Float16* __restrict__ qh,
                                              const _Float16* __restrict__ kh,
                                              const _Float16* __restrict__ vt,
                                              _Float16* __restrict__ ctx) {
    __shared__ char lds[2 * 16384];   // buf: [K 8KB][V 8KB], x2 double-buffer

    int tid = threadIdx.x;
    int wid = tid >> 6, lane = tid & 63;
    int g = lane >> 4, c = lane & 15;

    // 512 blocks: xcd = bid%8 -> 4 heads per XCD (K+V = 2MB, L2-resident)
    int bid = blockIdx.x;
    int xcd = bid & 7;
    int rest = bid >> 3;                  // 0..63
    int bh = xcd * 4 + (rest >> 4);       // 0..31
    int qc = rest & 15;                   // 16 chunks of 128 q-rows
    int q0 = qc * 128 + wid * 16;

    const _Float16* qp = qh + ((size_t)bh * LL + q0) * 64;
    const char* kg = (const char*)(kh + (size_t)bh * LL * 64);   // [L][64] contiguous tile: 8KB per KVBLK
    const char* vg = (const char*)(vt + (size_t)bh * 64 * LL);   // [dv=64][L]

    half8v qf0 = *(const half8v*)(qp + c * 64 + g * 8);
    half8v qf1 = *(const half8v*)(qp + c * 64 + 32 + g * 8);

    // ---- staging geometry: 8 waves x 1KB per tile; HW writes ldsbase + lane*16
    int pK   = wid * 1024 + lane * 16;            // byte offset in 8KB tile
    int rowS = pK >> 7;                           // tile row (128B rows)
    int srcK = (pK & ~127) | ((pK & 127) ^ ((rowS & 7) << 4));   // pre-swizzled source
    size_t srcV = (size_t)rowS * (LL * 2) + (size_t)((pK & 127) ^ ((rowS & 7) << 4));

#define STAGE(buf, kb) do {                                                   \
        char* sK = lds + (buf) * 16384 + wid * 1024;                          \
        char* sV = lds + (buf) * 16384 + 8192 + wid * 1024;                   \
        GLOAD_LDS(kg + (size_t)(kb) * 8192 + srcK, sK);                       \
        GLOAD_LDS(vg + srcV + (size_t)(kb) * 128, sV);                        \
    } while (0)

    float4v o[4] = {};
    float m = -1e30f, lsum = 0.0f;
    int swzk_c = (c & 7) << 4;   // read-side swizzle term for V rows (row&7 == c&7)

    STAGE(0, 0);

    for (int kb = 0; kb < NKB; ++kb) {
        int cur = kb & 1;
        if (kb + 1 < NKB) {
            STAGE(cur ^ 1, kb + 1);
            asm volatile("s_waitcnt vmcnt(2)" ::: "memory");
        } else {
            asm volatile("s_waitcnt vmcnt(0)" ::: "memory");
        }
        asm volatile("s_barrier" ::: "memory");

        const char* lk = lds + cur * 16384;
        const char* lv = lk + 8192;

#pragma unroll
        for (int s = 0; s < 4; ++s) {
            int krow = s * 16 + c;
            int swzk = (krow & 7) << 4;    // == swzk_c, but keep explicit
            half8v kf0 = *(const half8v*)(lk + krow * 128 + ((g * 16) ^ swzk));
            half8v kf1 = *(const half8v*)(lk + krow * 128 + ((g * 16 + 64) ^ swzk));
            float4v sv = {};
            sv = __builtin_amdgcn_mfma_f32_16x16x32_f16(kf0, qf0, sv, 0, 0, 0);
            sv = __builtin_amdgcn_mfma_f32_16x16x32_f16(kf1, qf1, sv, 0, 0, 0);

            float pmax = fmaxf(fmaxf(sv[0], sv[1]), fmaxf(sv[2], sv[3]));
            pmax = fmaxf(pmax, __shfl_xor(pmax, 16));
            pmax = fmaxf(pmax, __shfl_xor(pmax, 32));

            if (__any(pmax > m + 3.0f)) {          // deferred rescale (T13)
                float mn = fmaxf(m, pmax);
                float sc = __builtin_amdgcn_exp2f(m - mn);
                lsum *= sc;
#pragma unroll
                for (int t = 0; t < 4; ++t) o[t] *= sc;
                m = mn;
            }

            float p0 = __builtin_amdgcn_exp2f(sv[0] - m);
            float p1 = __builtin_amdgcn_exp2f(sv[1] - m);
            float p2 = __builtin_amdgcn_exp2f(sv[2] - m);
            float p3 = __builtin_amdgcn_exp2f(sv[3] - m);
            lsum += (p0 + p1) + (p2 + p3);
            half4v ph;
            ph[0] = (_Float16)p0; ph[1] = (_Float16)p1;
            ph[2] = (_Float16)p2; ph[3] = (_Float16)p3;

            int vcol = (s * 32 + g * 8) ^ swzk_c;
#pragma unroll
            for (int t = 0; t < 4; ++t) {
                half4v vf = *(const half4v*)(lv + (t * 16 + c) * 128 + vcol);
                o[t] = __builtin_amdgcn_mfma_f32_16x16x16f16(vf, ph, o[t], 0, 0, 0);
            }
        }

        asm volatile("s_barrier" ::: "memory");
    }
#undef STAGE

    lsum += __shfl_xor(lsum, 16);
    lsum += __shfl_xor(lsum, 32);
    float inv = 1.0f / lsum;

    _Float16* cp = ctx + ((size_t)bh * LL + q0 + c) * 64 + g * 4;
#pragma unroll
    for (int t = 0; t < 4; ++t) {
        half4v hv;
#pragma unroll
        for (int r = 0; r < 4; ++r) hv[r] = (_Float16)(o[t][r] * inv);
        *(half4v*)(cp + t * 16) = hv;
    }
}

// ---------------- output projection: [8192,512] @ [512,64] ----------------
__global__ __launch_bounds__(64) void k_oproj(const _Float16* __restrict__ ctx,
                                              const _Float16* __restrict__ wo2t,
                                              const float* __restrict__ bo,
                                              float* __restrict__ out) {
    int lane = threadIdx.x & 63;
    int g = lane >> 4, c = lane & 15;
    int m0 = blockIdx.x * 16;
    int b = m0 >> 11, l = m0 & 2047;
    const _Float16* cbase = ctx + ((size_t)b * HH * LL + l) * 64;

    float4v acc[4] = {};
#pragma unroll
    for (int kc = 0; kc < 16; ++kc) {
        int hh = kc >> 1;
        const _Float16* ap = cbase + (size_t)hh * LL * 64 + c * 64 + (kc & 1) * 32 + g * 8;
        half8v a = *(const half8v*)(ap);
#pragma unroll
        for (int t = 0; t < 4; ++t) {
            half8v bf = *(const half8v*)(wo2t + (t * 16 + c) * 512 + kc * 32 + g * 8);
            acc[t] = __builtin_amdgcn_mfma_f32_16x16x32_f16(a, bf, acc[t], 0, 0, 0);
        }
    }
#pragma unroll
    for (int t = 0; t < 4; ++t) {
        float bias = bo[t * 16 + c];
#pragma unroll
        for (int r = 0; r < 4; ++r) {
            int mm = m0 + g * 4 + r;
            out[mm * 64 + t * 16 + c] = acc[t][r] + bias;
        }
    }
}

// ---------------------------------------------------------------------------
extern "C" void kernel_launch(void* const* d_in, const int* in_sizes, int n_in,
                              void* d_out, int out_size, void* d_ws, size_t ws_size,
                              hipStream_t stream) {
    const float* x  = (const float*)d_in[0];
    const float* wq = (const float*)d_in[1];
    const float* bq = (const float*)d_in[2];
    const float* wk = (const float*)d_in[3];
    const float* bk = (const float*)d_in[4];
    const float* wv = (const float*)d_in[5];
    const float* bv = (const float*)d_in[6];
    const float* wo = (const float*)d_in[7];
    const float* bo = (const float*)d_in[8];
    float* out = (float*)d_out;

    char* ws = (char*)d_ws;
    _Float16* xh    = (_Float16*)(ws);                       // 1 MB
    _Float16* wt    = (_Float16*)(ws + 1048576);             // 192 KB
    float*    biasc = (float*)   (ws + 1245184);             // 6 KB
    _Float16* wo2t  = (_Float16*)(ws + 1251328);             // 64 KB
    _Float16* qh    = (_Float16*)(ws + 1316864);             // 8 MB
    _Float16* kh    = (_Float16*)(ws + 1316864 + 1ull * 8388608);
    _Float16* vt    = (_Float16*)(ws + 1316864 + 2ull * 8388608);
    _Float16* ctx   = (_Float16*)(ws + 1316864 + 3ull * 8388608);

    hipLaunchKernelGGL(k_prep_x,  dim3(512),      dim3(256), 0, stream, x, xh);
    hipLaunchKernelGGL(k_prep_w,  dim3(384),      dim3(256), 0, stream, wq, bq, wk, bk, wv, bv, wt, biasc);
    hipLaunchKernelGGL(k_prep_wo, dim3(128),      dim3(256), 0, stream, wo, wo2t);
    hipLaunchKernelGGL(k_proj,    dim3(128, 24),  dim3(256), 0, stream, xh, wt, biasc, qh, kh, vt);
    hipLaunchKernelGGL(k_attn,    dim3(512),      dim3(512), 0, stream, qh, kh, vt, ctx);
    hipLaunchKernelGGL(k_oproj,   dim3(512),      dim3(64),  0, stream, ctx, wo2t, bo, out);
}